// Round 6
// baseline (613.191 us; speedup 1.0000x reference)
//
#include <hip/hip_runtime.h>
#include <hip/hip_bf16.h>
#include <stdint.h>

#define B_   8
#define C_   512
#define NPIX 4096

typedef __attribute__((ext_vector_type(8))) short bf16x8;
typedef __attribute__((ext_vector_type(4))) float f32x4;
typedef __attribute__((ext_vector_type(16))) float f32x16;

__device__ __forceinline__ uint16_t f2bf(float f) {
    union { float f; uint32_t u; } v; v.f = f;
    uint32_t u = v.u;
    return (uint16_t)((u + 0x7FFFu + ((u >> 16) & 1u)) >> 16);
}

// pack 2 floats -> 2 bf16 in a u32 (compiler emits v_cvt_pk_bf16_f32)
__device__ __forceinline__ uint32_t pk2(float a, float b) {
    union { __hip_bfloat162 h; uint32_t u; } c;
    c.h = __float22bfloat162_rn(make_float2(a, b));
    return c.u;
}

// ---------------- projection: out = W(OxC) * X(CxN) + bias, bf16 output ----
// TRANS=true : out[b][n][o]   (for q_t, k_t; O==64)
// TRANS=false: out[b][o][n]   (for v)
template<bool TRANS>
__global__ __launch_bounds__(256, 2) void proj_kernel(
    const float* __restrict__ X, const float* __restrict__ W,
    const float* __restrict__ bias, uint16_t* __restrict__ out,
    int O, float scale)
{
    __shared__ char xt[64 * 128];   // [n][c] bf16, byte = n*128 + 2c ^ ((n&7)<<4)
    const int b  = blockIdx.z;
    const int o0 = blockIdx.y * 64;
    const int n0 = blockIdx.x * 64;
    const int t = threadIdx.x, w = t >> 6, l = t & 63;
    const int l15 = l & 15, lg = l >> 4;
    const float* Xb = X + (size_t)b * C_ * NPIX + n0;

    f32x4 acc[4] = {};

    for (int cc = 0; cc < C_; cc += 64) {
        __syncthreads();
        #pragma unroll
        for (int i = 0; i < 16; i += 2) {
            int c = w * 16 + i;
            float f0 = Xb[(size_t)(cc + c) * NPIX + l];
            float f1 = Xb[(size_t)(cc + c + 1) * NPIX + l];
            uint32_t pair = pk2(f0, f1);
            int byte = (l * 128 + c * 2) ^ ((l & 7) << 4);
            *(uint32_t*)(xt + byte) = pair;
        }
        __syncthreads();
        #pragma unroll
        for (int kk = 0; kk < 2; kk++) {
            int o  = o0 + w * 16 + l15;
            int cb = cc + kk * 32 + lg * 8;
            float4 wa = *(const float4*)&W[(size_t)o * C_ + cb];
            float4 wb = *(const float4*)&W[(size_t)o * C_ + cb + 4];
            union { bf16x8 v; uint32_t u[4]; } afu;
            afu.u[0] = pk2(wa.x, wa.y); afu.u[1] = pk2(wa.z, wa.w);
            afu.u[2] = pk2(wb.x, wb.y); afu.u[3] = pk2(wb.z, wb.w);
            #pragma unroll
            for (int jt = 0; jt < 4; jt++) {
                int n = jt * 16 + l15;
                int byte = (n * 128 + (kk * 32 + lg * 8) * 2) ^ ((n & 7) << 4);
                bf16x8 bfr = *(bf16x8*)(xt + byte);
                acc[jt] = __builtin_amdgcn_mfma_f32_16x16x32_bf16(afu.v, bfr, acc[jt], 0, 0, 0);
            }
        }
    }
    int og = o0 + w * 16 + lg * 4;
    #pragma unroll
    for (int jt = 0; jt < 4; jt++) {
        int n = n0 + jt * 16 + l15;
        #pragma unroll
        for (int r = 0; r < 4; r++) {
            float v = (acc[jt][r] + bias[og + r]) * scale;
            if (TRANS) out[((size_t)b * NPIX + n) * 64 + og + r] = f2bf(v);
            else       out[((size_t)b * (size_t)O + og + r) * NPIX + n] = f2bf(v);
        }
    }
}

// -------- fused attention: barrier-free, LDS-free, in-register P -----------
// Each wave independently owns 64 Q-rows x 64 channels. 32x32x16 MFMA,
// swapped QK^T (S^T = K*Q^T): lane(i=l&31, h=l>>5) holds S^T[j][i] for
// j = (r&3)+8*(r>>2)+4h. No-max softmax (|S|<<60). P stays in registers:
// PV B-frag (k=j=8h+e per 16-j half) assembled from packed bf16 pairs via
// 8x shfl_xor(32) per tile. No __shared__, no __syncthreads in the kernel.
__global__ __launch_bounds__(256, 2) void attn_kernel(
    const uint16_t* __restrict__ qT, const uint16_t* __restrict__ kT,
    const uint16_t* __restrict__ vB, const float* __restrict__ X,
    const float* __restrict__ gamma_p, float* __restrict__ out)
{
    const int id  = blockIdx.x;
    const int xcd = id & 7, slot = id >> 3;
    const int g   = xcd + 8 * (slot >> 6);     // 16 groups of 64 blocks per XCD
    const int qt  = slot & 63;
    const int b   = g >> 1, cb = g & 1;
    const int i0  = qt * 64;

    const int t = threadIdx.x, w = t >> 6, l = t & 63;
    const int l31 = l & 31, h = l >> 5;
    const int c0 = cb * 256 + w * 64;

    // Q B-frags: q8[it][dc]: i = i0+it*32+l31, k(d) = dc*16 + h*8 + e
    bf16x8 q8[2][4];
    {
        const uint16_t* qrow = qT + ((size_t)b * NPIX + i0 + l31) * 64 + h * 8;
        #pragma unroll
        for (int it = 0; it < 2; it++)
            #pragma unroll
            for (int dc = 0; dc < 4; dc++)
                q8[it][dc] = *(const bf16x8*)(qrow + it * (32 * 64) + dc * 16);
    }

    f32x16 oacc[2][2] = {};   // [ct][it] : O^T tiles (32c x 32i each)
    float lp0 = 0.f, lp1 = 0.f;  // per-lane row-sum partials (h-half of j)

    // K A-frag: row j = j0 + l31, k(d) = dc*16 + h*8 + e
    const uint16_t* kbase = kT + (size_t)b * NPIX * 64 + (size_t)l31 * 64 + h * 8;
    // V A-frag: row c = c0 + ct*32 + l31, k(j) = j0 + jh*16 + h*8 + e
    const uint16_t* vbase = vB + ((size_t)b * C_ + c0 + l31) * NPIX + h * 8;

    bf16x8 kA[4], kB[4], vA[4], vBr[4];

    auto loadK = [&](bf16x8 (&kf)[4], int j0) {
        #pragma unroll
        for (int dc = 0; dc < 4; dc++)
            kf[dc] = *(const bf16x8*)(kbase + (size_t)j0 * 64 + dc * 16);
    };
    auto loadV = [&](bf16x8 (&vf)[4], int j0) {
        #pragma unroll
        for (int jh = 0; jh < 2; jh++)
            #pragma unroll
            for (int ct = 0; ct < 2; ct++)
                vf[jh * 2 + ct] = *(const bf16x8*)(vbase + (size_t)ct * (32 * NPIX) + j0 + jh * 16);
    };

    // process one 32x32 S^T tile: exp2, row-sum partial, pack, redistribute
    // into PV B-frag words p[jh][0..3] (k-pairs (0,1),(2,3),(4,5),(6,7))
    auto process = [&](const f32x16& S, uint32_t (&p)[2][4], float& lp) {
        float e[16];
        #pragma unroll
        for (int r = 0; r < 16; r++) e[r] = exp2f(fminf(S[r], 60.f));
        lp += (((e[0]+e[1])+(e[2]+e[3])) + ((e[4]+e[5])+(e[6]+e[7])))
            + (((e[8]+e[9])+(e[10]+e[11])) + ((e[12]+e[13])+(e[14]+e[15])));
        uint32_t a[8], x[8];
        #pragma unroll
        for (int q = 0; q < 8; q++) a[q] = pk2(e[2*q], e[2*q+1]);   // j = 8(q>>1)+4h+2(q&1)+{0,1}
        #pragma unroll
        for (int q = 0; q < 8; q++) x[q] = __shfl_xor(a[q], 32);
        // jh=0 (j=0..15): lane needs j = 8h+{0..7}
        p[0][0] = h ? x[2] : a[0];  p[0][1] = h ? x[3] : a[1];
        p[0][2] = h ? a[2] : x[0];  p[0][3] = h ? a[3] : x[1];
        // jh=1 (j=16..31): lane needs j = 16+8h+{0..7}
        p[1][0] = h ? x[6] : a[4];  p[1][1] = h ? x[7] : a[5];
        p[1][2] = h ? a[6] : x[4];  p[1][3] = h ? a[7] : x[5];
    };

    auto STEP = [&](bf16x8 (&kf)[4], bf16x8 (&vf)[4], int j0) {
        f32x16 S0{}, S1{};
        __builtin_amdgcn_s_setprio(1);
        #pragma unroll
        for (int dc = 0; dc < 4; dc++)
            S0 = __builtin_amdgcn_mfma_f32_32x32x16_bf16(kf[dc], q8[0][dc], S0, 0, 0, 0);
        #pragma unroll
        for (int dc = 0; dc < 4; dc++)
            S1 = __builtin_amdgcn_mfma_f32_32x32x16_bf16(kf[dc], q8[1][dc], S1, 0, 0, 0);
        __builtin_amdgcn_s_setprio(0);
        if (j0 + 64 < NPIX) loadK(kf, j0 + 64);   // kf dead after QK issue

        uint32_t p0[2][4], p1[2][4];
        process(S0, p0, lp0);
        process(S1, p1, lp1);

        __builtin_amdgcn_s_setprio(1);
        #pragma unroll
        for (int jh = 0; jh < 2; jh++) {
            union { uint32_t u[4]; bf16x8 v; } f0, f1;
            #pragma unroll
            for (int q = 0; q < 4; q++) { f0.u[q] = p0[jh][q]; f1.u[q] = p1[jh][q]; }
            #pragma unroll
            for (int ct = 0; ct < 2; ct++) {
                oacc[ct][0] = __builtin_amdgcn_mfma_f32_32x32x16_bf16(vf[jh*2+ct], f0.v, oacc[ct][0], 0, 0, 0);
                oacc[ct][1] = __builtin_amdgcn_mfma_f32_32x32x16_bf16(vf[jh*2+ct], f1.v, oacc[ct][1], 0, 0, 0);
            }
        }
        __builtin_amdgcn_s_setprio(0);
        if (j0 + 64 < NPIX) loadV(vf, j0 + 64);   // vf dead after PV issue
    };

    loadK(kA, 0);  loadV(vA, 0);
    loadK(kB, 32); loadV(vBr, 32);

    #pragma unroll 1
    for (int j0 = 0; j0 < NPIX; j0 += 64) {
        STEP(kA, vA, j0);
        STEP(kB, vBr, j0 + 32);
    }

    // ---- epilogue: out = gamma * (O/l) + x ----
    float gamma = gamma_p[0];
    float lt0 = lp0 + __shfl_xor(lp0, 32);
    float lt1 = lp1 + __shfl_xor(lp1, 32);
    float rl0 = 1.0f / lt0, rl1 = 1.0f / lt1;
    #pragma unroll
    for (int ct = 0; ct < 2; ct++)
        #pragma unroll
        for (int it = 0; it < 2; it++) {
            float rl = it ? rl1 : rl0;
            int n = i0 + it * 32 + l31;
            #pragma unroll
            for (int r = 0; r < 16; r++) {
                int c = c0 + ct * 32 + (r & 3) + 8 * (r >> 2) + 4 * h;
                size_t idx = ((size_t)b * C_ + c) * NPIX + n;
                out[idx] = gamma * (oacc[ct][it][r] * rl) + X[idx];
            }
        }
}

extern "C" void kernel_launch(void* const* d_in, const int* in_sizes, int n_in,
                              void* d_out, int out_size, void* d_ws, size_t ws_size,
                              hipStream_t stream) {
    const float* x     = (const float*)d_in[0];
    const float* y     = (const float*)d_in[1];
    const float* z     = (const float*)d_in[2];
    const float* Wq    = (const float*)d_in[3];
    const float* bq    = (const float*)d_in[4];
    const float* Wk    = (const float*)d_in[5];
    const float* bk    = (const float*)d_in[6];
    const float* Wv    = (const float*)d_in[7];
    const float* bv    = (const float*)d_in[8];
    const float* gamma = (const float*)d_in[9];
    float* out = (float*)d_out;

    uint16_t* qT = (uint16_t*)d_ws;                       // [8][4096][64] bf16
    uint16_t* kT = qT + (size_t)B_ * NPIX * 64;           // [8][4096][64] bf16
    uint16_t* vb = kT + (size_t)B_ * NPIX * 64;           // [8][512][4096] bf16

    dim3 blk(256);
    // q pre-scaled by log2(e) so softmax uses exp2 directly
    proj_kernel<true ><<<dim3(64, 1, 8), blk, 0, stream>>>(x, Wq, bq, qT, 64, 1.4426950408889634f);
    proj_kernel<true ><<<dim3(64, 1, 8), blk, 0, stream>>>(y, Wk, bk, kT, 64, 1.0f);
    proj_kernel<false><<<dim3(64, 8, 8), blk, 0, stream>>>(z, Wv, bv, vb, 512, 1.0f);
    attn_kernel<<<dim3(1024), blk, 0, stream>>>(qT, kT, vb, x, gamma, out);
}

// Round 7
// 427.896 us; speedup vs baseline: 1.4330x; 1.4330x over previous
//
#include <hip/hip_runtime.h>
#include <hip/hip_bf16.h>
#include <stdint.h>

#define B_   8
#define C_   512
#define NPIX 4096

typedef __attribute__((ext_vector_type(8))) short bf16x8;
typedef __attribute__((ext_vector_type(4))) float f32x4;

__device__ __forceinline__ uint16_t f2bf(float f) {
    union { float f; uint32_t u; } v; v.f = f;
    uint32_t u = v.u;
    return (uint16_t)((u + 0x7FFFu + ((u >> 16) & 1u)) >> 16);
}

// pack 2 floats -> 2 bf16 in a u32 (compiler emits v_cvt_pk_bf16_f32)
__device__ __forceinline__ uint32_t pk2(float a, float b) {
    union { __hip_bfloat162 h; uint32_t u; } c;
    c.h = __float22bfloat162_rn(make_float2(a, b));
    return c.u;
}

// ---------------- projection: out = W(OxC) * X(CxN) + bias, bf16 output ----
// TRANS=true : out[b][n][o]   (for q_t, k_t; O==64)
// TRANS=false: out[b][o][n]   (for v)
template<bool TRANS>
__global__ __launch_bounds__(256, 2) void proj_kernel(
    const float* __restrict__ X, const float* __restrict__ W,
    const float* __restrict__ bias, uint16_t* __restrict__ out,
    int O, float scale)
{
    __shared__ char xt[64 * 128];   // [n][c] bf16, byte = n*128 + 2c ^ ((n&7)<<4)
    const int b  = blockIdx.z;
    const int o0 = blockIdx.y * 64;
    const int n0 = blockIdx.x * 64;
    const int t = threadIdx.x, w = t >> 6, l = t & 63;
    const int l15 = l & 15, lg = l >> 4;
    const float* Xb = X + (size_t)b * C_ * NPIX + n0;

    f32x4 acc[4] = {};

    for (int cc = 0; cc < C_; cc += 64) {
        __syncthreads();
        #pragma unroll
        for (int i = 0; i < 16; i += 2) {
            int c = w * 16 + i;
            float f0 = Xb[(size_t)(cc + c) * NPIX + l];
            float f1 = Xb[(size_t)(cc + c + 1) * NPIX + l];
            uint32_t pair = pk2(f0, f1);
            int byte = (l * 128 + c * 2) ^ ((l & 7) << 4);
            *(uint32_t*)(xt + byte) = pair;
        }
        __syncthreads();
        #pragma unroll
        for (int kk = 0; kk < 2; kk++) {
            int o  = o0 + w * 16 + l15;
            int cb = cc + kk * 32 + lg * 8;
            float4 wa = *(const float4*)&W[(size_t)o * C_ + cb];
            float4 wb = *(const float4*)&W[(size_t)o * C_ + cb + 4];
            union { bf16x8 v; uint32_t u[4]; } afu;
            afu.u[0] = pk2(wa.x, wa.y); afu.u[1] = pk2(wa.z, wa.w);
            afu.u[2] = pk2(wb.x, wb.y); afu.u[3] = pk2(wb.z, wb.w);
            #pragma unroll
            for (int jt = 0; jt < 4; jt++) {
                int n = jt * 16 + l15;
                int byte = (n * 128 + (kk * 32 + lg * 8) * 2) ^ ((n & 7) << 4);
                bf16x8 bfr = *(bf16x8*)(xt + byte);
                acc[jt] = __builtin_amdgcn_mfma_f32_16x16x32_bf16(afu.v, bfr, acc[jt], 0, 0, 0);
            }
        }
    }
    int og = o0 + w * 16 + lg * 4;
    #pragma unroll
    for (int jt = 0; jt < 4; jt++) {
        int n = n0 + jt * 16 + l15;
        #pragma unroll
        for (int r = 0; r < 4; r++) {
            float v = (acc[jt][r] + bias[og + r]) * scale;
            if (TRANS) out[((size_t)b * NPIX + n) * 64 + og + r] = f2bf(v);
            else       out[((size_t)b * (size_t)O + og + r) * NPIX + n] = f2bf(v);
        }
    }
}

// ---------------- fused flash attention, no-max softmax --------------------
// r5 structure (shared softmax, 1 barrier/step, double-buffered P) with the
// barrier's vmcnt(0) drain removed: only the LDS P-tile needs cross-wave
// visibility, so barrier = s_waitcnt lgkmcnt(0) + s_barrier. Global K/V
// register prefetches stay in flight across barriers (consumed a full step
// later via compiler-inserted vmcnt). pwrite placed right after the barrier
// to maximize its distance to the next lgkmcnt(0) drain.
__global__ __launch_bounds__(256, 2) void attn_kernel(
    const uint16_t* __restrict__ qT, const uint16_t* __restrict__ kT,
    const uint16_t* __restrict__ vB, const float* __restrict__ X,
    const float* __restrict__ gamma_p, float* __restrict__ out)
{
    __shared__ char  Pl[2][64 * 128];   // P[i][j] bf16, byte=i*128+2j ^ ((i&7)<<4)
    __shared__ float lsum[64][5];       // final l merge, padded stride 5

    const int id  = blockIdx.x;
    const int xcd = id & 7, slot = id >> 3;
    const int g   = xcd + 8 * (slot >> 6);     // 16 groups of 64 blocks per XCD
    const int qt  = slot & 63;
    const int b   = g >> 1, cb = g & 1;
    const int i0  = qt * 64;

    const int t = threadIdx.x, w = t >> 6, l = t & 63;
    const int l15 = l & 15, lg = l >> 4;
    const int c0 = cb * 256 + w * 64;

    // LDS-only barrier: waves' ds_writes visible, global loads NOT drained.
    auto barrier_lds = [&]() {
        asm volatile("s_waitcnt lgkmcnt(0)" ::: "memory");
        __builtin_amdgcn_s_barrier();
    };

    // Q fragments (B-operand of swapped QK): col i = l15, k-elems d = lg*8..
    bf16x8 q8[4][2];
    #pragma unroll
    for (int it = 0; it < 4; it++)
        #pragma unroll
        for (int kk = 0; kk < 2; kk++)
            q8[it][kk] = *(const bf16x8*)&qT[((size_t)b * NPIX + i0 + it*16 + l15) * 64 + kk*32 + lg*8];

    f32x4 oacc[4][4] = {};    // [ct][it] : O^T[c][i]
    float l_part[4] = {0.f, 0.f, 0.f, 0.f};

    const uint16_t* kTb = kT + (size_t)b * NPIX * 64;
    const uint16_t* vBb = vB + ((size_t)b * C_ + c0) * NPIX;
    const uint16_t* kROW = kTb + (size_t)(w * 16 + l15) * 64 + lg * 8;

    bf16x8 k8[2], vreg[8];
    f32x4 s[4];
    uint2  pk[4];

    auto loadK = [&](int step) {
        const uint16_t* p = kROW + (size_t)step * (64 * 64);
        k8[0] = *(const bf16x8*)p;
        k8[1] = *(const bf16x8*)(p + 32);
    };
    auto loadV = [&](int step) {
        const uint16_t* p = vBb + step * 64 + lg * 8;
        #pragma unroll
        for (int kk = 0; kk < 2; kk++)
            #pragma unroll
            for (int ct = 0; ct < 4; ct++)
                vreg[kk*4+ct] = *(const bf16x8*)(p + (size_t)(ct*16 + l15) * NPIX + kk*32);
    };
    auto QK = [&]() {
        #pragma unroll
        for (int it = 0; it < 4; it++) s[it] = f32x4{0.f, 0.f, 0.f, 0.f};
        __builtin_amdgcn_s_setprio(1);
        #pragma unroll
        for (int kk = 0; kk < 2; kk++)
            #pragma unroll
            for (int it = 0; it < 4; it++)
                s[it] = __builtin_amdgcn_mfma_f32_16x16x32_bf16(k8[kk], q8[it][kk], s[it], 0, 0, 0);
        __builtin_amdgcn_s_setprio(0);
    };
    // P = exp2(clamp(s)); accumulate row-sums per lane; pack to bf16
    auto Pcompute = [&]() {
        #pragma unroll
        for (int it = 0; it < 4; it++) {
            float e0 = exp2f(fminf(s[it][0], 60.f));
            float e1 = exp2f(fminf(s[it][1], 60.f));
            float e2 = exp2f(fminf(s[it][2], 60.f));
            float e3 = exp2f(fminf(s[it][3], 60.f));
            l_part[it] += (e0 + e1) + (e2 + e3);
            pk[it].x = pk2(e0, e1);
            pk[it].y = pk2(e2, e3);
        }
    };
    auto pwrite = [&](char* P) {
        #pragma unroll
        for (int it = 0; it < 4; it++) {
            int i = it * 16 + l15;
            int byte = (i * 128 + (w * 16 + lg * 4) * 2) ^ ((i & 7) << 4);
            *(uint2*)(P + byte) = pk[it];
        }
    };
    auto PV = [&](const char* P) {
        __builtin_amdgcn_s_setprio(1);
        #pragma unroll
        for (int kk = 0; kk < 2; kk++) {
            bf16x8 pb[4];
            #pragma unroll
            for (int it = 0; it < 4; it++) {
                int i = it * 16 + l15;
                int byte = (i * 128 + kk * 64 + lg * 16) ^ ((i & 7) << 4);
                pb[it] = *(const bf16x8*)(P + byte);
            }
            #pragma unroll
            for (int ct = 0; ct < 4; ct++) {
                bf16x8 v8 = vreg[kk*4 + ct];
                #pragma unroll
                for (int it = 0; it < 4; it++)
                    oacc[ct][it] = __builtin_amdgcn_mfma_f32_16x16x32_bf16(v8, pb[it], oacc[ct][it], 0, 0, 0);
            }
        }
        __builtin_amdgcn_s_setprio(0);
    };

    // ---- prologue: steps 0 and 1 produced; V(0), K(2) in flight ----
    loadK(0);
    QK();                 // s = step 0
    loadK(1);
    loadV(0);
    Pcompute();           // pk = step 0
    pwrite(Pl[0]);
    QK();                 // s = step 1 (k8 = K(1))
    loadK(2);
    Pcompute();           // pk = step 1

    // ---- steady state: 1 LDS-only barrier per step ----
    #pragma unroll 1
    for (int jt_ = 1; jt_ < 64; ++jt_) {
        barrier_lds();
        pwrite(Pl[jt_ & 1]);        // pk = step jt_ (computed last iter)
        PV(Pl[(jt_ - 1) & 1]);      // vreg = V(jt_-1)
        loadV(jt_);                 // in flight across next barrier
        if (jt_ < 63) {
            QK();                   // s = step jt_+1 (k8 = K(jt_+1))
            if (jt_ < 62) loadK(jt_ + 2);
            Pcompute();             // pk = step jt_+1
        }
    }
    barrier_lds();
    PV(Pl[1]);                      // step 63

    // ---- final l reduction: lanes -> wave, wave -> block ----
    #pragma unroll
    for (int it = 0; it < 4; it++) {
        float v = l_part[it];
        v += __shfl_xor(v, 16);
        v += __shfl_xor(v, 32);
        if (lg == 0) lsum[it * 16 + l15][w] = v;
    }
    __syncthreads();

    // ---- epilogue: out = gamma * (O/l) + x ; coalesced along i (=n) ----
    float gamma = gamma_p[0];
    float rl[4];
    #pragma unroll
    for (int it = 0; it < 4; it++) {
        int i = it * 16 + l15;
        rl[it] = 1.0f / ((lsum[i][0] + lsum[i][1]) + (lsum[i][2] + lsum[i][3]));
    }
    #pragma unroll
    for (int ct = 0; ct < 4; ct++)
        #pragma unroll
        for (int r = 0; r < 4; r++) {
            int c = c0 + ct * 16 + lg * 4 + r;
            #pragma unroll
            for (int it = 0; it < 4; it++) {
                int n = i0 + it * 16 + l15;
                size_t idx = ((size_t)b * C_ + c) * NPIX + n;
                out[idx] = gamma * (oacc[ct][it][r] * rl[it]) + X[idx];
            }
        }
}

extern "C" void kernel_launch(void* const* d_in, const int* in_sizes, int n_in,
                              void* d_out, int out_size, void* d_ws, size_t ws_size,
                              hipStream_t stream) {
    const float* x     = (const float*)d_in[0];
    const float* y     = (const float*)d_in[1];
    const float* z     = (const float*)d_in[2];
    const float* Wq    = (const float*)d_in[3];
    const float* bq    = (const float*)d_in[4];
    const float* Wk    = (const float*)d_in[5];
    const float* bk    = (const float*)d_in[6];
    const float* Wv    = (const float*)d_in[7];
    const float* bv    = (const float*)d_in[8];
    const float* gamma = (const float*)d_in[9];
    float* out = (float*)d_out;

    uint16_t* qT = (uint16_t*)d_ws;                       // [8][4096][64] bf16
    uint16_t* kT = qT + (size_t)B_ * NPIX * 64;           // [8][4096][64] bf16
    uint16_t* vb = kT + (size_t)B_ * NPIX * 64;           // [8][512][4096] bf16

    dim3 blk(256);
    // q pre-scaled by log2(e) so softmax uses exp2 directly
    proj_kernel<true ><<<dim3(64, 1, 8), blk, 0, stream>>>(x, Wq, bq, qT, 64, 1.4426950408889634f);
    proj_kernel<true ><<<dim3(64, 1, 8), blk, 0, stream>>>(y, Wk, bk, kT, 64, 1.0f);
    proj_kernel<false><<<dim3(64, 8, 8), blk, 0, stream>>>(z, Wv, bv, vb, 512, 1.0f);
    attn_kernel<<<dim3(1024), blk, 0, stream>>>(qT, kT, vb, x, gamma, out);
}